// Round 1
// baseline (6501.358 us; speedup 1.0000x reference)
//
#include <hip/hip_runtime.h>

#define CCH 256
#define BB 4

// ---------------- 2x2 average pool (iterated => equals s-window mean) ----------------
__global__ __launch_bounds__(256) void pool2_kernel(const float* __restrict__ in, float* __restrict__ out,
                                                    int NP, int Ho, int Wo) {
    int idx = blockIdx.x * 256 + threadIdx.x;
    int total = NP * Ho * Wo;
    if (idx >= total) return;
    int xo = idx % Wo;
    int yo = (idx / Wo) % Ho;
    int p  = idx / (Wo * Ho);
    int Wi = Wo * 2;
    const float* ip = in + (((size_t)p * (Ho * 2) + (2 * yo)) * (size_t)Wi + 2 * xo);
    float s = ip[0] + ip[1] + ip[Wi] + ip[Wi + 1];
    out[idx] = 0.25f * s;
}

// ---------------- per-pixel inverse L2 norm over channels (for f2) ----------------
__global__ __launch_bounds__(256) void invnorm_kernel(const float* __restrict__ f, float* __restrict__ invn,
                                                      int H, int W) {
    int idx = blockIdx.x * 256 + threadIdx.x;
    int HW = H * W;
    if (idx >= BB * HW) return;
    int pix = idx % HW;
    int b = idx / HW;
    const float* p = f + (size_t)b * CCH * HW + pix;
    float s = 0.f;
    #pragma unroll 4
    for (int c = 0; c < CCH; ++c) { float v = *p; s = fmaf(v, v, s); p += HW; }
    invn[idx] = 1.f / fmaxf(sqrtf(s), 1e-12f);
}

// ---------------- depth term: dw * exp(-|d1-d2|) ----------------
__global__ __launch_bounds__(256) void dterm_kernel(const float* __restrict__ d1, const float* __restrict__ d2,
                                                    const float* __restrict__ dw, float* __restrict__ dt, int n) {
    int i = blockIdx.x * 256 + threadIdx.x;
    if (i >= n) return;
    dt[i] = dw[0] * expf(-fabsf(d1[i] - d2[i]));
}

// ---------------- correlation ----------------
// One thread per output pixel, 81 accumulators, loop over 256 channels in NCHW.
// Rows are clamped (garbage reads stay in-buffer and are masked at the end);
// SAFE variant bound-checks against the whole buffer, used only for c=0 and c=C-1
// where clamped-row + x-halo could under/overrun the allocation itself.
template<bool SAFE>
__device__ __forceinline__ void corr_step(const float* __restrict__ f2, int g,
                                          const int* rowoff, float a, float* acc, int ntot) {
    #pragma unroll
    for (int k = 0; k < 9; ++k) {
        int rb = g + rowoff[k];
        #pragma unroll
        for (int j = 0; j < 9; ++j) {
            int gi = rb + (4 - j);
            float v;
            if (SAFE) {
                v = (gi >= 0 && gi < ntot) ? f2[gi] : 0.f;
            } else {
                v = f2[gi];
            }
            acc[k * 9 + j] = fmaf(a, v, acc[k * 9 + j]);
        }
    }
}

__global__ __launch_bounds__(256) void corr_kernel(const float* __restrict__ f1, const float* __restrict__ f2,
                                                   const float* __restrict__ invn2, const float* __restrict__ dt,
                                                   float* __restrict__ out, int H, int W) {
    int HW = H * W;
    int idx = blockIdx.x * 256 + threadIdx.x;
    if (idx >= BB * HW) return;
    int x = idx % W;
    int y = (idx / W) % H;
    int b = idx / HW;
    int pixbase = (b * CCH * H + y) * W + x;

    int rowoff[9];
    #pragma unroll
    for (int k = 0; k < 9; ++k) {
        int sy = y - (k - 4);
        int cy = min(max(sy, 0), H - 1);
        rowoff[k] = (cy - y) * W;
    }

    float acc[81];
    #pragma unroll
    for (int o = 0; o < 81; ++o) acc[o] = 0.f;
    float s1 = 0.f;

    const float* ap = f1 + pixbase;
    int g = pixbase;
    int ntot = BB * CCH * HW;

    { // c = 0 (bounds-checked)
        float a = *ap; s1 = fmaf(a, a, s1);
        corr_step<true>(f2, g, rowoff, a, acc, ntot);
        ap += HW; g += HW;
    }
    #pragma unroll 1
    for (int c = 1; c < CCH - 1; ++c) {
        float a = *ap; s1 = fmaf(a, a, s1);
        corr_step<false>(f2, g, rowoff, a, acc, ntot);
        ap += HW; g += HW;
    }
    { // c = C-1 (bounds-checked)
        float a = *ap; s1 = fmaf(a, a, s1);
        corr_step<true>(f2, g, rowoff, a, acc, ntot);
    }

    float invn1 = 1.f / fmaxf(sqrtf(s1), 1e-12f);
    float dterm = dt[idx];
    float* op = out + (size_t)b * 81 * HW + (size_t)y * W + x;
    int ibase = b * HW;
    #pragma unroll
    for (int k = 0; k < 9; ++k) {
        int sy = y - (k - 4);
        bool vy = (sy >= 0) && (sy < H);
        #pragma unroll
        for (int j = 0; j < 9; ++j) {
            int sx = x - (j - 4);
            bool v = vy && (sx >= 0) && (sx < W);
            float r = 0.f;
            if (v) r = acc[k * 9 + j] * invn1 * invn2[ibase + sy * W + sx];
            op[(size_t)(k * 9 + j) * HW] = r + dterm;
        }
    }
}

extern "C" void kernel_launch(void* const* d_in, const int* in_sizes, int n_in,
                              void* d_out, int out_size, void* d_ws, size_t ws_size,
                              hipStream_t stream) {
    const float* f1 = (const float*)d_in[0];
    const float* f2 = (const float*)d_in[1];
    const float* d1 = (const float*)d_in[2];
    const float* d2 = (const float*)d_in[3];
    const float* dw = (const float*)d_in[4];
    float* out = (float*)d_out;
    float* ws = (float*)d_ws;

    // ---- workspace carve (floats) ----
    size_t o = 0;
    float* pf1_1 = ws + o; o += (size_t)4 * 256 * 64 * 96;   // 6291456
    float* pf2_1 = ws + o; o += (size_t)4 * 256 * 64 * 96;
    float* pf1_2 = ws + o; o += (size_t)4 * 256 * 32 * 48;   // 1572864
    float* pf2_2 = ws + o; o += (size_t)4 * 256 * 32 * 48;
    float* pf1_3 = ws + o; o += (size_t)4 * 256 * 16 * 24;   // 393216
    float* pf2_3 = ws + o; o += (size_t)4 * 256 * 16 * 24;
    float* pd1_1 = ws + o; o += (size_t)4 * 64 * 96;
    float* pd2_1 = ws + o; o += (size_t)4 * 64 * 96;
    float* pd1_2 = ws + o; o += (size_t)4 * 32 * 48;
    float* pd2_2 = ws + o; o += (size_t)4 * 32 * 48;
    float* pd1_3 = ws + o; o += (size_t)4 * 16 * 24;
    float* pd2_3 = ws + o; o += (size_t)4 * 16 * 24;
    float* invn2_0 = ws + o; o += (size_t)4 * 128 * 192;
    float* invn2_1 = ws + o; o += (size_t)4 * 64 * 96;
    float* invn2_2 = ws + o; o += (size_t)4 * 32 * 48;
    float* invn2_3 = ws + o; o += (size_t)4 * 16 * 24;
    float* dt_0 = ws + o; o += (size_t)4 * 128 * 192;
    float* dt_1 = ws + o; o += (size_t)4 * 64 * 96;
    float* dt_2 = ws + o; o += (size_t)4 * 32 * 48;
    float* dt_3 = ws + o; o += (size_t)4 * 16 * 24;

    auto blocks = [](int n) { return dim3((unsigned)((n + 255) / 256)); };

    // ---- pooling chains ----
    pool2_kernel<<<blocks(4 * 256 * 64 * 96), 256, 0, stream>>>(f1, pf1_1, 4 * 256, 64, 96);
    pool2_kernel<<<blocks(4 * 256 * 64 * 96), 256, 0, stream>>>(f2, pf2_1, 4 * 256, 64, 96);
    pool2_kernel<<<blocks(4 * 256 * 32 * 48), 256, 0, stream>>>(pf1_1, pf1_2, 4 * 256, 32, 48);
    pool2_kernel<<<blocks(4 * 256 * 32 * 48), 256, 0, stream>>>(pf2_1, pf2_2, 4 * 256, 32, 48);
    pool2_kernel<<<blocks(4 * 256 * 16 * 24), 256, 0, stream>>>(pf1_2, pf1_3, 4 * 256, 16, 24);
    pool2_kernel<<<blocks(4 * 256 * 16 * 24), 256, 0, stream>>>(pf2_2, pf2_3, 4 * 256, 16, 24);

    pool2_kernel<<<blocks(4 * 64 * 96), 256, 0, stream>>>(d1, pd1_1, 4, 64, 96);
    pool2_kernel<<<blocks(4 * 64 * 96), 256, 0, stream>>>(d2, pd2_1, 4, 64, 96);
    pool2_kernel<<<blocks(4 * 32 * 48), 256, 0, stream>>>(pd1_1, pd1_2, 4, 32, 48);
    pool2_kernel<<<blocks(4 * 32 * 48), 256, 0, stream>>>(pd2_1, pd2_2, 4, 32, 48);
    pool2_kernel<<<blocks(4 * 16 * 24), 256, 0, stream>>>(pd1_2, pd1_3, 4, 16, 24);
    pool2_kernel<<<blocks(4 * 16 * 24), 256, 0, stream>>>(pd2_2, pd2_3, 4, 16, 24);

    // ---- depth terms ----
    dterm_kernel<<<blocks(4 * 128 * 192), 256, 0, stream>>>(d1, d2, dw, dt_0, 4 * 128 * 192);
    dterm_kernel<<<blocks(4 * 64 * 96), 256, 0, stream>>>(pd1_1, pd2_1, dw, dt_1, 4 * 64 * 96);
    dterm_kernel<<<blocks(4 * 32 * 48), 256, 0, stream>>>(pd1_2, pd2_2, dw, dt_2, 4 * 32 * 48);
    dterm_kernel<<<blocks(4 * 16 * 24), 256, 0, stream>>>(pd1_3, pd2_3, dw, dt_3, 4 * 16 * 24);

    // ---- f2 inverse norms ----
    invnorm_kernel<<<blocks(4 * 128 * 192), 256, 0, stream>>>(f2, invn2_0, 128, 192);
    invnorm_kernel<<<blocks(4 * 64 * 96), 256, 0, stream>>>(pf2_1, invn2_1, 64, 96);
    invnorm_kernel<<<blocks(4 * 32 * 48), 256, 0, stream>>>(pf2_2, invn2_2, 32, 48);
    invnorm_kernel<<<blocks(4 * 16 * 24), 256, 0, stream>>>(pf2_3, invn2_3, 16, 24);

    // ---- correlations (f1 norm fused) ----
    corr_kernel<<<blocks(4 * 128 * 192), 256, 0, stream>>>(f1, f2, invn2_0, dt_0, out, 128, 192);
    corr_kernel<<<blocks(4 * 64 * 96), 256, 0, stream>>>(pf1_1, pf2_1, invn2_1, dt_1, out + 7962624, 64, 96);
    corr_kernel<<<blocks(4 * 32 * 48), 256, 0, stream>>>(pf1_2, pf2_2, invn2_2, dt_2, out + 9953280, 32, 48);
    corr_kernel<<<blocks(4 * 16 * 24), 256, 0, stream>>>(pf1_3, pf2_3, invn2_3, dt_3, out + 10450944, 16, 24);
}

// Round 2
// 363.564 us; speedup vs baseline: 17.8823x; 17.8823x over previous
//
#include <hip/hip_runtime.h>
#include <hip/hip_bf16.h>

typedef __attribute__((ext_vector_type(8))) __bf16 bf16x8;
typedef __attribute__((ext_vector_type(4))) float f32x4;
typedef unsigned short ushort_t;
typedef unsigned int uint_t;

#define CCH 256
#define BB 4

__device__ __forceinline__ ushort_t f2b(float v) {
    __hip_bfloat16 h = __float2bfloat16(v);
    return *reinterpret_cast<ushort_t*>(&h);
}

// =====================================================================
// prep: NCHW fp32 -> NHWC raw bf16 + per-pixel invnorm + 2x2 pooled fp32
// block handles (b, row pair 2*yo..2*yo+1, x chunk of XC)
// =====================================================================
template<int XC, bool HAS_POOL>
__global__ __launch_bounds__(256) void prep_kernel(
    const float* __restrict__ fin, ushort_t* __restrict__ fout,
    float* __restrict__ invn, float* __restrict__ pooled,
    int H, int W)
{
    constexpr int NP = 2 * XC;       // pixels per block
    constexpr int STR = NP + 1;      // LDS stride (bank-spread)
    __shared__ float lds[64 * STR];
    __shared__ float ssqs[NP * 2];

    int nxc = W / XC;
    int xc = blockIdx.x % nxc;
    int yo = (blockIdx.x / nxc) % (H >> 1);
    int b  = blockIdx.x / (nxc * (H >> 1));
    int xb = xc * XC;
    int t  = threadIdx.x;

    int p3p = t >> 1, p3q = t & 1;   // phase 3: pixel, c-half
    bool act3 = (t < 2 * NP);
    int prow = p3p / XC, ppx = p3p % XC;
    size_t obase = 0;
    if (act3) obase = ((size_t)((b * H + 2 * yo + prow) * W) + xb + ppx) * (size_t)CCH;

    float myssq = 0.f;
    for (int kc = 0; kc < 4; ++kc) {
        // phase 1: stage 64c x 2row x XC
        #pragma unroll
        for (int j = 0; j < NP / 4; ++j) {
            int e = t + 256 * j;
            int x = e % XC;
            int row = (e / XC) & 1;
            int ci = e / NP;
            float v = fin[((size_t)((b << 8) + (kc << 6) + ci) * H + 2 * yo + row) * W + xb + x];
            lds[ci * STR + row * XC + x] = v;
        }
        __syncthreads();
        // phase 3: bf16 NHWC write (64B per thread, coalesced) + ssq
        if (act3) {
            uint_t uu[16];
            #pragma unroll
            for (int j = 0; j < 32; ++j) {
                float v = lds[(p3q * 32 + j) * STR + p3p];
                myssq = fmaf(v, v, myssq);
                ushort_t bb = f2b(v);
                if ((j & 1) == 0) uu[j >> 1] = (uint_t)bb;
                else              uu[j >> 1] |= ((uint_t)bb) << 16;
            }
            ushort_t* dst = fout + obase + (kc << 6) + (p3q << 5);
            *reinterpret_cast<uint4*>(dst +  0) = make_uint4(uu[0],  uu[1],  uu[2],  uu[3]);
            *reinterpret_cast<uint4*>(dst +  8) = make_uint4(uu[4],  uu[5],  uu[6],  uu[7]);
            *reinterpret_cast<uint4*>(dst + 16) = make_uint4(uu[8],  uu[9],  uu[10], uu[11]);
            *reinterpret_cast<uint4*>(dst + 24) = make_uint4(uu[12], uu[13], uu[14], uu[15]);
        }
        // phase 4: 2x2 pooled fp32 for next level
        if (HAS_POOL && t < 192) {
            constexpr int XO = XC / 2;
            constexpr int NC = 192 / XO;
            int xo = t % XO;
            int cib = t / XO;
            #pragma unroll
            for (int j = 0; j < 64 / NC; ++j) {
                int ci = cib + NC * j;
                float s = lds[ci * STR + 2 * xo] + lds[ci * STR + 2 * xo + 1]
                        + lds[ci * STR + XC + 2 * xo] + lds[ci * STR + XC + 2 * xo + 1];
                pooled[((size_t)((b << 8) + (kc << 6) + ci) * (H >> 1) + yo) * (W >> 1) + xc * XO + xo] = 0.25f * s;
            }
        }
        __syncthreads();
    }
    if (act3) ssqs[t] = myssq;
    __syncthreads();
    if (t < NP) {
        float s = ssqs[2 * t] + ssqs[2 * t + 1];
        float iv = 1.f / fmaxf(sqrtf(s), 1e-12f);
        invn[(size_t)(b * H + 2 * yo + (t / XC)) * W + xb + (t % XC)] = iv;
    }
}

// =====================================================================
// MFMA correlation: one wave per 4x4 output tile, 12x12 window = 9 N-tiles
// acc[t] = A(16 f1 pixels x K) * B(K x 16 window pixels), K=256 in 8 chunks
// OOB window pixels read a memset-zero block (exact zero-pad semantics).
// =====================================================================
__global__ __launch_bounds__(256) void corr_mfma_kernel(
    const ushort_t* __restrict__ f1n, const ushort_t* __restrict__ f2n,
    const float* __restrict__ invn1, const float* __restrict__ invn2,
    const float* __restrict__ dt, float* __restrict__ out,
    int H, int W, int TX, int TY, int zoff)
{
    int wid  = threadIdx.x >> 6;
    int lane = threadIdx.x & 63;
    int tile = blockIdx.x * 4 + wid;
    int ntiles = BB * TY * TX;
    if (tile >= ntiles) return;
    int tx = tile % TX;
    int ty = (tile / TX) % TY;
    int b  = tile / (TX * TY);
    int x0 = tx * 4, y0 = ty * 4;

    int col = lane & 15;
    int kg  = lane >> 4;

    // A address: pixel m = col -> (iy,ix); k = kg*8 + e
    int iyA = col >> 2, ixA = col & 3;
    int a_off = (((b * H + y0 + iyA) * W) + x0 + ixA) * CCH + kg * 8;

    // B addresses for 9 N-tiles
    int b_off[9];
    uint_t vmask = 0;
    #pragma unroll
    for (int tt = 0; tt < 9; ++tt) {
        int w = tt * 16 + col;
        int wy = w / 12, wx = w % 12;
        int py = y0 + wy - 4, px = x0 + wx - 4;
        bool v = (py >= 0) && (py < H) && (px >= 0) && (px < W);
        b_off[tt] = v ? (((b * H + py) * W + px) * CCH + kg * 8) : (zoff + kg * 8);
        if (v) vmask |= (1u << tt);
    }

    f32x4 acc[9] = {};
    #pragma unroll
    for (int kb = 0; kb < 8; ++kb) {
        bf16x8 av = *reinterpret_cast<const bf16x8*>(f1n + a_off + kb * 32);
        #pragma unroll
        for (int tt = 0; tt < 9; ++tt) {
            bf16x8 bv = *reinterpret_cast<const bf16x8*>(f2n + b_off[tt] + kb * 32);
            acc[tt] = __builtin_amdgcn_mfma_f32_16x16x32_bf16(av, bv, acc[tt], 0, 0, 0);
        }
    }

    // epilogue: lane holds D[m][w] with m = kg*4 + r, w = 16*tt + col
    float inv1[4], dts[4];
    #pragma unroll
    for (int r = 0; r < 4; ++r) {
        int m = kg * 4 + r;
        int iy = m >> 2, ix = m & 3;
        int pix = (b * H + y0 + iy) * W + x0 + ix;
        inv1[r] = invn1[pix];
        dts[r]  = dt[pix];
    }
    #pragma unroll
    for (int tt = 0; tt < 9; ++tt) {
        int w = tt * 16 + col;
        int wy = w / 12, wx = w % 12;
        int py = y0 + wy - 4, px = x0 + wx - 4;
        float i2 = ((vmask >> tt) & 1u) ? invn2[(b * H + py) * W + px] : 0.f;
        #pragma unroll
        for (int r = 0; r < 4; ++r) {
            int m = kg * 4 + r;
            int iy = m >> 2, ix = m & 3;
            int oy = iy + 8 - wy, ox = ix + 8 - wx;
            if (oy >= 0 && oy < 9 && ox >= 0 && ox < 9) {
                int o = oy * 9 + ox;
                out[((size_t)(b * 81 + o) * H + (y0 + iy)) * W + (x0 + ix)]
                    = acc[tt][r] * inv1[r] * i2 + dts[r];
            }
        }
    }
}

// =====================================================================
// small helper kernels (depth chain) — also used by the fallback path
// =====================================================================
__global__ __launch_bounds__(256) void pool2_kernel(const float* __restrict__ in, float* __restrict__ out,
                                                    int NP_, int Ho, int Wo) {
    int idx = blockIdx.x * 256 + threadIdx.x;
    int total = NP_ * Ho * Wo;
    if (idx >= total) return;
    int xo = idx % Wo;
    int yo = (idx / Wo) % Ho;
    int p  = idx / (Wo * Ho);
    int Wi = Wo * 2;
    const float* ip = in + (((size_t)p * (Ho * 2) + (2 * yo)) * (size_t)Wi + 2 * xo);
    float s = ip[0] + ip[1] + ip[Wi] + ip[Wi + 1];
    out[idx] = 0.25f * s;
}

__global__ __launch_bounds__(256) void dterm_kernel(const float* __restrict__ d1, const float* __restrict__ d2,
                                                    const float* __restrict__ dw, float* __restrict__ dt, int n) {
    int i = blockIdx.x * 256 + threadIdx.x;
    if (i >= n) return;
    dt[i] = dw[0] * expf(-fabsf(d1[i] - d2[i]));
}

// ------------------- fallback (round-1) kernels -------------------
__global__ __launch_bounds__(256) void invnorm_kernel(const float* __restrict__ f, float* __restrict__ invn,
                                                      int H, int W) {
    int idx = blockIdx.x * 256 + threadIdx.x;
    int HW = H * W;
    if (idx >= BB * HW) return;
    int pix = idx % HW;
    int b = idx / HW;
    const float* p = f + (size_t)b * CCH * HW + pix;
    float s = 0.f;
    #pragma unroll 4
    for (int c = 0; c < CCH; ++c) { float v = *p; s = fmaf(v, v, s); p += HW; }
    invn[idx] = 1.f / fmaxf(sqrtf(s), 1e-12f);
}

template<bool SAFE>
__device__ __forceinline__ void corr_step(const float* __restrict__ f2, int g,
                                          const int* rowoff, float a, float* acc, int ntot) {
    #pragma unroll
    for (int k = 0; k < 9; ++k) {
        int rb = g + rowoff[k];
        #pragma unroll
        for (int j = 0; j < 9; ++j) {
            int gi = rb + (4 - j);
            float v;
            if (SAFE) v = (gi >= 0 && gi < ntot) ? f2[gi] : 0.f;
            else      v = f2[gi];
            acc[k * 9 + j] = fmaf(a, v, acc[k * 9 + j]);
        }
    }
}

__global__ __launch_bounds__(256) void corr_kernel(const float* __restrict__ f1, const float* __restrict__ f2,
                                                   const float* __restrict__ invn2, const float* __restrict__ dt,
                                                   float* __restrict__ out, int H, int W) {
    int HW = H * W;
    int idx = blockIdx.x * 256 + threadIdx.x;
    if (idx >= BB * HW) return;
    int x = idx % W;
    int y = (idx / W) % H;
    int b = idx / HW;
    int pixbase = (b * CCH * H + y) * W + x;

    int rowoff[9];
    #pragma unroll
    for (int k = 0; k < 9; ++k) {
        int sy = y - (k - 4);
        int cy = min(max(sy, 0), H - 1);
        rowoff[k] = (cy - y) * W;
    }
    float acc[81];
    #pragma unroll
    for (int o = 0; o < 81; ++o) acc[o] = 0.f;
    float s1 = 0.f;
    const float* ap = f1 + pixbase;
    int g = pixbase;
    int ntot = BB * CCH * HW;
    { float a = *ap; s1 = fmaf(a, a, s1); corr_step<true>(f2, g, rowoff, a, acc, ntot); ap += HW; g += HW; }
    #pragma unroll 1
    for (int c = 1; c < CCH - 1; ++c) {
        float a = *ap; s1 = fmaf(a, a, s1);
        corr_step<false>(f2, g, rowoff, a, acc, ntot);
        ap += HW; g += HW;
    }
    { float a = *ap; s1 = fmaf(a, a, s1); corr_step<true>(f2, g, rowoff, a, acc, ntot); }

    float invn1v = 1.f / fmaxf(sqrtf(s1), 1e-12f);
    float dtv = dt[idx];
    float* op = out + (size_t)b * 81 * HW + (size_t)y * W + x;
    int ibase = b * HW;
    #pragma unroll
    for (int k = 0; k < 9; ++k) {
        int sy = y - (k - 4);
        bool vy = (sy >= 0) && (sy < H);
        #pragma unroll
        for (int j = 0; j < 9; ++j) {
            int sx = x - (j - 4);
            bool v = vy && (sx >= 0) && (sx < W);
            float r = 0.f;
            if (v) r = acc[k * 9 + j] * invn1v * invn2[ibase + sy * W + sx];
            op[(size_t)(k * 9 + j) * HW] = r + dtv;
        }
    }
}

// =====================================================================
extern "C" void kernel_launch(void* const* d_in, const int* in_sizes, int n_in,
                              void* d_out, int out_size, void* d_ws, size_t ws_size,
                              hipStream_t stream) {
    const float* f1 = (const float*)d_in[0];
    const float* f2 = (const float*)d_in[1];
    const float* d1 = (const float*)d_in[2];
    const float* d2 = (const float*)d_in[3];
    const float* dw = (const float*)d_in[4];
    float* out = (float*)d_out;
    float* ws  = (float*)d_ws;

    auto blocks = [](int n) { return dim3((unsigned)((n + 255) / 256)); };

    // ---------------- float workspace carve ----------------
    size_t o = 0;
    float* p1f1 = ws + o; o += (size_t)4 * 256 * 64 * 96;
    float* p2f1 = ws + o; o += (size_t)4 * 256 * 32 * 48;
    float* p3f1 = ws + o; o += (size_t)4 * 256 * 16 * 24;
    float* p1f2 = ws + o; o += (size_t)4 * 256 * 64 * 96;
    float* p2f2 = ws + o; o += (size_t)4 * 256 * 32 * 48;
    float* p3f2 = ws + o; o += (size_t)4 * 256 * 16 * 24;
    float* in1_0 = ws + o; o += (size_t)4 * 128 * 192;
    float* in1_1 = ws + o; o += (size_t)4 * 64 * 96;
    float* in1_2 = ws + o; o += (size_t)4 * 32 * 48;
    float* in1_3 = ws + o; o += (size_t)4 * 16 * 24;
    float* in2_0 = ws + o; o += (size_t)4 * 128 * 192;
    float* in2_1 = ws + o; o += (size_t)4 * 64 * 96;
    float* in2_2 = ws + o; o += (size_t)4 * 32 * 48;
    float* in2_3 = ws + o; o += (size_t)4 * 16 * 24;
    float* pd1_1 = ws + o; o += (size_t)4 * 64 * 96;
    float* pd1_2 = ws + o; o += (size_t)4 * 32 * 48;
    float* pd1_3 = ws + o; o += (size_t)4 * 16 * 24;
    float* pd2_1 = ws + o; o += (size_t)4 * 64 * 96;
    float* pd2_2 = ws + o; o += (size_t)4 * 32 * 48;
    float* pd2_3 = ws + o; o += (size_t)4 * 16 * 24;
    float* dt_0 = ws + o; o += (size_t)4 * 128 * 192;
    float* dt_1 = ws + o; o += (size_t)4 * 64 * 96;
    float* dt_2 = ws + o; o += (size_t)4 * 32 * 48;
    float* dt_3 = ws + o; o += (size_t)4 * 16 * 24;
    o = (o + 7) & ~(size_t)7;   // 16B align the short region

    // ---------------- bf16 (ushort) workspace carve ----------------
    ushort_t* sws = (ushort_t*)(ws + o);
    const size_t L0 = (size_t)4 * 128 * 192 * 256;   // 25165824
    const size_t L1 = (size_t)4 * 64 * 96 * 256;     //  6291456
    const size_t L2 = (size_t)4 * 32 * 48 * 256;     //  1572864
    const size_t L3 = (size_t)4 * 16 * 24 * 256;     //   393216
    const size_t FT = L0 + L1 + L2 + L3;             // 33423360
    ushort_t* f1n0 = sws;
    ushort_t* f1n1 = f1n0 + L0;
    ushort_t* f1n2 = f1n1 + L1;
    ushort_t* f1n3 = f1n2 + L2;
    ushort_t* f2n0 = sws + FT;
    ushort_t* f2n1 = f2n0 + L0;
    ushort_t* f2n2 = f2n1 + L1;
    ushort_t* f2n3 = f2n2 + L2;
    ushort_t* zblk = sws + 2 * FT;                    // 256 shorts of zeros
    size_t need = o * 4 + (2 * FT + 256) * 2;

    if (ws_size < need) {
        // -------- fallback: round-1 fp32 path (known-good) --------
        size_t q = 0;
        float* a1 = ws + q; q += (size_t)4 * 256 * 64 * 96;
        float* a2 = ws + q; q += (size_t)4 * 256 * 64 * 96;
        float* b1 = ws + q; q += (size_t)4 * 256 * 32 * 48;
        float* b2 = ws + q; q += (size_t)4 * 256 * 32 * 48;
        float* c1 = ws + q; q += (size_t)4 * 256 * 16 * 24;
        float* c2 = ws + q; q += (size_t)4 * 256 * 16 * 24;
        float* e1 = ws + q; q += (size_t)4 * 64 * 96;
        float* e2 = ws + q; q += (size_t)4 * 64 * 96;
        float* g1 = ws + q; q += (size_t)4 * 32 * 48;
        float* g2 = ws + q; q += (size_t)4 * 32 * 48;
        float* h1 = ws + q; q += (size_t)4 * 16 * 24;
        float* h2 = ws + q; q += (size_t)4 * 16 * 24;
        float* i0 = ws + q; q += (size_t)4 * 128 * 192;
        float* i1 = ws + q; q += (size_t)4 * 64 * 96;
        float* i2 = ws + q; q += (size_t)4 * 32 * 48;
        float* i3 = ws + q; q += (size_t)4 * 16 * 24;
        float* t0 = ws + q; q += (size_t)4 * 128 * 192;
        float* t1 = ws + q; q += (size_t)4 * 64 * 96;
        float* t2 = ws + q; q += (size_t)4 * 32 * 48;
        float* t3 = ws + q; q += (size_t)4 * 16 * 24;
        pool2_kernel<<<blocks(4*256*64*96), 256, 0, stream>>>(f1, a1, 4*256, 64, 96);
        pool2_kernel<<<blocks(4*256*64*96), 256, 0, stream>>>(f2, a2, 4*256, 64, 96);
        pool2_kernel<<<blocks(4*256*32*48), 256, 0, stream>>>(a1, b1, 4*256, 32, 48);
        pool2_kernel<<<blocks(4*256*32*48), 256, 0, stream>>>(a2, b2, 4*256, 32, 48);
        pool2_kernel<<<blocks(4*256*16*24), 256, 0, stream>>>(b1, c1, 4*256, 16, 24);
        pool2_kernel<<<blocks(4*256*16*24), 256, 0, stream>>>(b2, c2, 4*256, 16, 24);
        pool2_kernel<<<blocks(4*64*96), 256, 0, stream>>>(d1, e1, 4, 64, 96);
        pool2_kernel<<<blocks(4*64*96), 256, 0, stream>>>(d2, e2, 4, 64, 96);
        pool2_kernel<<<blocks(4*32*48), 256, 0, stream>>>(e1, g1, 4, 32, 48);
        pool2_kernel<<<blocks(4*32*48), 256, 0, stream>>>(e2, g2, 4, 32, 48);
        pool2_kernel<<<blocks(4*16*24), 256, 0, stream>>>(g1, h1, 4, 16, 24);
        pool2_kernel<<<blocks(4*16*24), 256, 0, stream>>>(g2, h2, 4, 16, 24);
        dterm_kernel<<<blocks(4*128*192), 256, 0, stream>>>(d1, d2, dw, t0, 4*128*192);
        dterm_kernel<<<blocks(4*64*96), 256, 0, stream>>>(e1, e2, dw, t1, 4*64*96);
        dterm_kernel<<<blocks(4*32*48), 256, 0, stream>>>(g1, g2, dw, t2, 4*32*48);
        dterm_kernel<<<blocks(4*16*24), 256, 0, stream>>>(h1, h2, dw, t3, 4*16*24);
        invnorm_kernel<<<blocks(4*128*192), 256, 0, stream>>>(f2, i0, 128, 192);
        invnorm_kernel<<<blocks(4*64*96), 256, 0, stream>>>(a2, i1, 64, 96);
        invnorm_kernel<<<blocks(4*32*48), 256, 0, stream>>>(b2, i2, 32, 48);
        invnorm_kernel<<<blocks(4*16*24), 256, 0, stream>>>(c2, i3, 16, 24);
        corr_kernel<<<blocks(4*128*192), 256, 0, stream>>>(f1, f2, i0, t0, out, 128, 192);
        corr_kernel<<<blocks(4*64*96), 256, 0, stream>>>(a1, a2, i1, t1, out + 7962624, 64, 96);
        corr_kernel<<<blocks(4*32*48), 256, 0, stream>>>(b1, b2, i2, t2, out + 9953280, 32, 48);
        corr_kernel<<<blocks(4*16*24), 256, 0, stream>>>(c1, c2, i3, t3, out + 10450944, 16, 24);
        return;
    }

    // ---------------- main MFMA path ----------------
    hipMemsetAsync(zblk, 0, 512, stream);

    // prep chains (f1 then f2; pooled fp32 feeds next level)
    prep_kernel<48, true ><<<dim3(4 * 64 * 4), 256, 0, stream>>>(f1,   f1n0, in1_0, p1f1, 128, 192);
    prep_kernel<48, true ><<<dim3(4 * 32 * 2), 256, 0, stream>>>(p1f1, f1n1, in1_1, p2f1, 64, 96);
    prep_kernel<48, true ><<<dim3(4 * 16 * 1), 256, 0, stream>>>(p2f1, f1n2, in1_2, p3f1, 32, 48);
    prep_kernel<24, false><<<dim3(4 *  8 * 1), 256, 0, stream>>>(p3f1, f1n3, in1_3, nullptr, 16, 24);
    prep_kernel<48, true ><<<dim3(4 * 64 * 4), 256, 0, stream>>>(f2,   f2n0, in2_0, p1f2, 128, 192);
    prep_kernel<48, true ><<<dim3(4 * 32 * 2), 256, 0, stream>>>(p1f2, f2n1, in2_1, p2f2, 64, 96);
    prep_kernel<48, true ><<<dim3(4 * 16 * 1), 256, 0, stream>>>(p2f2, f2n2, in2_2, p3f2, 32, 48);
    prep_kernel<24, false><<<dim3(4 *  8 * 1), 256, 0, stream>>>(p3f2, f2n3, in2_3, nullptr, 16, 24);

    // depth chain + depth terms
    pool2_kernel<<<blocks(4*64*96), 256, 0, stream>>>(d1, pd1_1, 4, 64, 96);
    pool2_kernel<<<blocks(4*64*96), 256, 0, stream>>>(d2, pd2_1, 4, 64, 96);
    pool2_kernel<<<blocks(4*32*48), 256, 0, stream>>>(pd1_1, pd1_2, 4, 32, 48);
    pool2_kernel<<<blocks(4*32*48), 256, 0, stream>>>(pd2_1, pd2_2, 4, 32, 48);
    pool2_kernel<<<blocks(4*16*24), 256, 0, stream>>>(pd1_2, pd1_3, 4, 16, 24);
    pool2_kernel<<<blocks(4*16*24), 256, 0, stream>>>(pd2_2, pd2_3, 4, 16, 24);
    dterm_kernel<<<blocks(4*128*192), 256, 0, stream>>>(d1, d2, dw, dt_0, 4*128*192);
    dterm_kernel<<<blocks(4*64*96), 256, 0, stream>>>(pd1_1, pd2_1, dw, dt_1, 4*64*96);
    dterm_kernel<<<blocks(4*32*48), 256, 0, stream>>>(pd1_2, pd2_2, dw, dt_2, 4*32*48);
    dterm_kernel<<<blocks(4*16*24), 256, 0, stream>>>(pd1_3, pd2_3, dw, dt_3, 4*16*24);

    // MFMA correlation per level. zoff = distance from f2n_l base to zblk.
    corr_mfma_kernel<<<dim3(6144 / 4), 256, 0, stream>>>(f1n0, f2n0, in1_0, in2_0, dt_0, out,            128, 192, 48, 32, (int)(2*FT - 0*0 - (size_t)(f2n0 - sws)));
    corr_mfma_kernel<<<dim3(1536 / 4), 256, 0, stream>>>(f1n1, f2n1, in1_1, in2_1, dt_1, out + 7962624,   64,  96, 24, 16, (int)(2*FT - (size_t)(f2n1 - sws)));
    corr_mfma_kernel<<<dim3( 384 / 4), 256, 0, stream>>>(f1n2, f2n2, in1_2, in2_2, dt_2, out + 9953280,   32,  48, 12,  8, (int)(2*FT - (size_t)(f2n2 - sws)));
    corr_mfma_kernel<<<dim3(  96 / 4), 256, 0, stream>>>(f1n3, f2n3, in1_3, in2_3, dt_3, out + 10450944,  16,  24,  6,  4, (int)(2*FT - (size_t)(f2n3 - sws)));
}

// Round 3
// 300.991 us; speedup vs baseline: 21.5998x; 1.2079x over previous
//
#include <hip/hip_runtime.h>
#include <hip/hip_bf16.h>

typedef __attribute__((ext_vector_type(8))) __bf16 bf16x8;
typedef __attribute__((ext_vector_type(4))) float f32x4;
typedef unsigned short ushort_t;
typedef unsigned int uint_t;

#define CCH 256
#define BB 4

__device__ __forceinline__ ushort_t f2b(float v) {
    __hip_bfloat16 h = __float2bfloat16(v);
    return *reinterpret_cast<ushort_t*>(&h);
}

__device__ __forceinline__ void gload16(const void* g, void* l) {
    __builtin_amdgcn_global_load_lds(
        (const __attribute__((address_space(1))) void*)g,
        (__attribute__((address_space(3))) void*)l, 16, 0, 0);
}

// =====================================================================
// prep2: NCHW fp32 -> NHWC raw bf16 + per-pixel invnorm + 2x2 pooled fp32
// blockIdx.y in {0,1} selects (f1-set, f2-set) — halves serialized prep time
// =====================================================================
template<int XC, bool HAS_POOL>
__global__ __launch_bounds__(256) void prep2_kernel(
    const float* __restrict__ fa, const float* __restrict__ fb,
    ushort_t* __restrict__ oa, ushort_t* __restrict__ ob,
    float* __restrict__ ia, float* __restrict__ ib,
    float* __restrict__ pa, float* __restrict__ pb,
    int H, int W)
{
    const float* fin = blockIdx.y ? fb : fa;
    ushort_t* fout   = blockIdx.y ? ob : oa;
    float* invn      = blockIdx.y ? ib : ia;
    float* pooled    = blockIdx.y ? pb : pa;

    constexpr int NP = 2 * XC;
    constexpr int STR = NP + 1;
    __shared__ float lds[64 * STR];
    __shared__ float ssqs[NP * 2];

    int nxc = W / XC;
    int xc = blockIdx.x % nxc;
    int yo = (blockIdx.x / nxc) % (H >> 1);
    int b  = blockIdx.x / (nxc * (H >> 1));
    int xb = xc * XC;
    int t  = threadIdx.x;

    int p3p = t >> 1, p3q = t & 1;
    bool act3 = (t < 2 * NP);
    int prow = p3p / XC, ppx = p3p % XC;
    size_t obase = 0;
    if (act3) obase = ((size_t)((b * H + 2 * yo + prow) * W) + xb + ppx) * (size_t)CCH;

    float myssq = 0.f;
    for (int kc = 0; kc < 4; ++kc) {
        #pragma unroll
        for (int j = 0; j < NP / 4; ++j) {
            int e = t + 256 * j;
            int x = e % XC;
            int row = (e / XC) & 1;
            int ci = e / NP;
            float v = fin[((size_t)((b << 8) + (kc << 6) + ci) * H + 2 * yo + row) * W + xb + x];
            lds[ci * STR + row * XC + x] = v;
        }
        __syncthreads();
        if (act3) {
            uint_t uu[16];
            #pragma unroll
            for (int j = 0; j < 32; ++j) {
                float v = lds[(p3q * 32 + j) * STR + p3p];
                myssq = fmaf(v, v, myssq);
                ushort_t bb = f2b(v);
                if ((j & 1) == 0) uu[j >> 1] = (uint_t)bb;
                else              uu[j >> 1] |= ((uint_t)bb) << 16;
            }
            ushort_t* dst = fout + obase + (kc << 6) + (p3q << 5);
            *reinterpret_cast<uint4*>(dst +  0) = make_uint4(uu[0],  uu[1],  uu[2],  uu[3]);
            *reinterpret_cast<uint4*>(dst +  8) = make_uint4(uu[4],  uu[5],  uu[6],  uu[7]);
            *reinterpret_cast<uint4*>(dst + 16) = make_uint4(uu[8],  uu[9],  uu[10], uu[11]);
            *reinterpret_cast<uint4*>(dst + 24) = make_uint4(uu[12], uu[13], uu[14], uu[15]);
        }
        if (HAS_POOL && t < 192) {
            constexpr int XO = XC / 2;
            constexpr int NC = 192 / XO;
            int xo = t % XO;
            int cib = t / XO;
            #pragma unroll
            for (int j = 0; j < 64 / NC; ++j) {
                int ci = cib + NC * j;
                float s = lds[ci * STR + 2 * xo] + lds[ci * STR + 2 * xo + 1]
                        + lds[ci * STR + XC + 2 * xo] + lds[ci * STR + XC + 2 * xo + 1];
                pooled[((size_t)((b << 8) + (kc << 6) + ci) * (H >> 1) + yo) * (W >> 1) + xc * XO + xo] = 0.25f * s;
            }
        }
        __syncthreads();
    }
    if (act3) ssqs[t] = myssq;
    __syncthreads();
    if (t < NP) {
        float s = ssqs[2 * t] + ssqs[2 * t + 1];
        float iv = 1.f / fmaxf(sqrtf(s), 1e-12f);
        invn[(size_t)(b * H + 2 * yo + (t / XC)) * W + xb + (t % XC)] = iv;
    }
}

// =====================================================================
// corr_mfma2: LDS-staged, double-buffered. Block = 16x8 output pixels,
// 4 waves, wave = 2 horizontally adjacent 4x4 subtiles sharing B-frags.
// Window 16x24 staged via global_load_lds, source-side XOR swizzle
// (wx ^= 4*(wy&1)) so B/A fragment ds_read_b128 is 2-way (free).
// LDS = exactly 64 KiB -> 2 blocks/CU.
// =====================================================================
__global__ __launch_bounds__(256, 2) void corr_mfma2_kernel(
    const ushort_t* __restrict__ f1n, const ushort_t* __restrict__ f2n,
    const float* __restrict__ invn1, const float* __restrict__ invn2,
    const float* __restrict__ dt, float* __restrict__ out,
    const ushort_t* __restrict__ zblk, int H, int W, int TX, int TY)
{
    __shared__ char smem[65536];
    char* As = smem;             // [buf:8192][kg:2048][reg:1024]
    char* Bs = smem + 16384;     // [buf:24576][kg:6144][reg:1024]

    // XCD-chunked swizzle (grid % 8 == 0 at every level)
    int bid = blockIdx.x;
    int cpx = gridDim.x >> 3;
    int swz = (bid & 7) * cpx + (bid >> 3);
    int tx = swz % TX;
    int ty = (swz / TX) % TY;
    int b  = swz / (TX * TY);
    int x0 = tx * 16, y0 = ty * 8;

    int tid = threadIdx.x;
    int w = tid >> 6, lane = tid & 63;
    int kg = lane >> 4, col = lane & 15;
    int r2 = col >> 2, c2 = col & 3;
    int sy = w >> 1, p = w & 1;

    // ---- staging pointers (fixed per lane; advance 32 shorts per chunk) ----
    const ushort_t* srcA[2]; char* ldsA[2];
    #pragma unroll
    for (int q = 0; q < 2; ++q) {
        int qq = w * 2 + q;
        int kgs = qq >> 1, reg = qq & 1;
        int slot = reg * 64 + lane;
        int ly = slot >> 4, lxp = slot & 15;
        int lx = lxp ^ (4 * (ly & 1));
        srcA[q] = f1n + ((size_t)((b * H + y0 + ly) * W) + x0 + lx) * CCH + kgs * 8;
        ldsA[q] = As + qq * 1024;
    }
    const ushort_t* srcB[6]; int advB[6]; char* ldsB[6];
    #pragma unroll
    for (int q = 0; q < 6; ++q) {
        int qq = w * 6 + q;
        int kgs = qq / 6, reg = qq % 6;
        int slot = reg * 64 + lane;
        int wy = slot / 24, wxp = slot % 24;
        int wx = wxp ^ (4 * (wy & 1));
        int py = y0 - 4 + wy, px = x0 - 4 + wx;
        bool v = (py >= 0) && (py < H) && (px >= 0) && (px < W);
        srcB[q] = v ? (f2n + ((size_t)((b * H + py) * W) + px) * CCH + kgs * 8) : zblk;
        advB[q] = v ? 32 : 0;
        ldsB[q] = Bs + qq * 1024;
    }

    // ---- fragment LDS byte offsets ----
    int aoff[2], boff[3][4];
    #pragma unroll
    for (int s = 0; s < 2; ++s) {
        int sxs = 2 * p + s;
        int ly = 4 * sy + r2;
        int lx = (4 * sxs + c2) ^ (4 * (ly & 1));
        aoff[s] = kg * 2048 + (ly * 16 + lx) * 16;
    }
    #pragma unroll
    for (int i = 0; i < 3; ++i)
        #pragma unroll
        for (int j = 0; j < 4; ++j) {
            int wy = 4 * (sy + i) + r2;
            int wx = (4 * (2 * p + j) + c2) ^ (4 * (wy & 1));
            boff[i][j] = kg * 6144 + (wy * 24 + wx) * 16;
        }

    f32x4 acc0[3][3] = {};
    f32x4 acc1[3][3] = {};

    // ---- prologue: stage chunk 0 into buf 0 ----
    #pragma unroll
    for (int q = 0; q < 2; ++q) { gload16(srcA[q], ldsA[q]); srcA[q] += 32; }
    #pragma unroll
    for (int q = 0; q < 6; ++q) { gload16(srcB[q], ldsB[q]); srcB[q] += advB[q]; }
    asm volatile("s_waitcnt vmcnt(0)" ::: "memory");
    __builtin_amdgcn_s_barrier();
    __builtin_amdgcn_sched_barrier(0);

    int buf = 0;
    #pragma unroll 1
    for (int kc = 0; kc < 8; ++kc) {
        if (kc < 7) {   // issue next-chunk stage BEFORE compute (overlap)
            int boA = (buf ^ 1) * 8192;
            int boB = (buf ^ 1) * 24576;
            #pragma unroll
            for (int q = 0; q < 2; ++q) { gload16(srcA[q], ldsA[q] + boA); srcA[q] += 32; }
            #pragma unroll
            for (int q = 0; q < 6; ++q) { gload16(srcB[q], ldsB[q] + boB); srcB[q] += advB[q]; }
        }
        const char* Ab = As + buf * 8192;
        const char* Bb = Bs + buf * 24576;
        bf16x8 av0 = *(const bf16x8*)(Ab + aoff[0]);
        bf16x8 av1 = *(const bf16x8*)(Ab + aoff[1]);
        #pragma unroll
        for (int i = 0; i < 3; ++i) {
            #pragma unroll
            for (int j = 0; j < 4; ++j) {
                bf16x8 bv = *(const bf16x8*)(Bb + boff[i][j]);
                if (j < 3) acc0[i][j]     = __builtin_amdgcn_mfma_f32_16x16x32_bf16(av0, bv, acc0[i][j], 0, 0, 0);
                if (j > 0) acc1[i][j - 1] = __builtin_amdgcn_mfma_f32_16x16x32_bf16(av1, bv, acc1[i][j - 1], 0, 0, 0);
            }
        }
        if (kc < 7) {
            __builtin_amdgcn_sched_barrier(0);
            asm volatile("s_waitcnt vmcnt(0)" ::: "memory");
            __builtin_amdgcn_s_barrier();
            __builtin_amdgcn_sched_barrier(0);
        }
        buf ^= 1;
    }

    // ---- epilogue ----
    float inv1v[2][4], dtv[2][4];
    #pragma unroll
    for (int s = 0; s < 2; ++s) {
        int sxs = 2 * p + s;
        #pragma unroll
        for (int rr = 0; rr < 4; ++rr) {
            int m = kg * 4 + rr;
            int iy = m >> 2, ix = m & 3;
            int pix = (b * H + y0 + 4 * sy + iy) * W + x0 + 4 * sxs + ix;
            inv1v[s][rr] = invn1[pix];
            dtv[s][rr]   = dt[pix];
        }
    }
    #pragma unroll
    for (int s = 0; s < 2; ++s) {
        int sxs = 2 * p + s;
        #pragma unroll
        for (int i = 0; i < 3; ++i) {
            #pragma unroll
            for (int jj = 0; jj < 3; ++jj) {
                int wy = 4 * (sy + i) + r2;
                int wxr = 4 * (sxs + jj) + c2;
                int py = y0 - 4 + wy, px = x0 - 4 + wxr;
                bool v = (py >= 0) && (py < H) && (px >= 0) && (px < W);
                float i2 = v ? invn2[(b * H + py) * W + px] : 0.f;
                f32x4 a = (s == 0) ? acc0[i][jj] : acc1[i][jj];
                #pragma unroll
                for (int rr = 0; rr < 4; ++rr) {
                    int m = kg * 4 + rr;
                    int iy = m >> 2, ix = m & 3;
                    int oy = iy + 8 - (4 * i + r2);
                    int ox = ix + 8 - (4 * jj + c2);
                    if (oy >= 0 && oy < 9 && ox >= 0 && ox < 9) {
                        int gy = y0 + 4 * sy + iy, gx = x0 + 4 * sxs + ix;
                        out[((size_t)(b * 81 + oy * 9 + ox) * H + gy) * W + gx]
                            = a[rr] * inv1v[s][rr] * i2 + dtv[s][rr];
                    }
                }
            }
        }
    }
}

// =====================================================================
// corr_mfma (round-2, known good) — used for L3 only (16x24, 24 blocks)
// =====================================================================
__global__ __launch_bounds__(256) void corr_mfma_kernel(
    const ushort_t* __restrict__ f1n, const ushort_t* __restrict__ f2n,
    const float* __restrict__ invn1, const float* __restrict__ invn2,
    const float* __restrict__ dt, float* __restrict__ out,
    int H, int W, int TX, int TY, int zoff)
{
    int wid  = threadIdx.x >> 6;
    int lane = threadIdx.x & 63;
    int tile = blockIdx.x * 4 + wid;
    int ntiles = BB * TY * TX;
    if (tile >= ntiles) return;
    int tx = tile % TX;
    int ty = (tile / TX) % TY;
    int b  = tile / (TX * TY);
    int x0 = tx * 4, y0 = ty * 4;

    int col = lane & 15;
    int kg  = lane >> 4;

    int iyA = col >> 2, ixA = col & 3;
    int a_off = (((b * H + y0 + iyA) * W) + x0 + ixA) * CCH + kg * 8;

    int b_off[9];
    uint_t vmask = 0;
    #pragma unroll
    for (int tt = 0; tt < 9; ++tt) {
        int w = tt * 16 + col;
        int wy = w / 12, wx = w % 12;
        int py = y0 + wy - 4, px = x0 + wx - 4;
        bool v = (py >= 0) && (py < H) && (px >= 0) && (px < W);
        b_off[tt] = v ? (((b * H + py) * W + px) * CCH + kg * 8) : (zoff + kg * 8);
        if (v) vmask |= (1u << tt);
    }

    f32x4 acc[9] = {};
    #pragma unroll
    for (int kb = 0; kb < 8; ++kb) {
        bf16x8 av = *reinterpret_cast<const bf16x8*>(f1n + a_off + kb * 32);
        #pragma unroll
        for (int tt = 0; tt < 9; ++tt) {
            bf16x8 bv = *reinterpret_cast<const bf16x8*>(f2n + b_off[tt] + kb * 32);
            acc[tt] = __builtin_amdgcn_mfma_f32_16x16x32_bf16(av, bv, acc[tt], 0, 0, 0);
        }
    }

    float inv1[4], dts[4];
    #pragma unroll
    for (int r = 0; r < 4; ++r) {
        int m = kg * 4 + r;
        int iy = m >> 2, ix = m & 3;
        int pix = (b * H + y0 + iy) * W + x0 + ix;
        inv1[r] = invn1[pix];
        dts[r]  = dt[pix];
    }
    #pragma unroll
    for (int tt = 0; tt < 9; ++tt) {
        int w = tt * 16 + col;
        int wy = w / 12, wx = w % 12;
        int py = y0 + wy - 4, px = x0 + wx - 4;
        float i2 = ((vmask >> tt) & 1u) ? invn2[(b * H + py) * W + px] : 0.f;
        #pragma unroll
        for (int r = 0; r < 4; ++r) {
            int m = kg * 4 + r;
            int iy = m >> 2, ix = m & 3;
            int oy = iy + 8 - wy, ox = ix + 8 - wx;
            if (oy >= 0 && oy < 9 && ox >= 0 && ox < 9) {
                int o = oy * 9 + ox;
                out[((size_t)(b * 81 + o) * H + (y0 + iy)) * W + (x0 + ix)]
                    = acc[tt][r] * inv1[r] * i2 + dts[r];
            }
        }
    }
}

// =====================================================================
// depth: one thread owns an 8x8 L0 patch; computes dt for all 4 levels.
// Replaces 6 pools + 4 dterm launches.
// =====================================================================
__global__ __launch_bounds__(256) void depth_kernel(
    const float* __restrict__ d1, const float* __restrict__ d2,
    const float* __restrict__ dw,
    float* __restrict__ dt0, float* __restrict__ dt1,
    float* __restrict__ dt2, float* __restrict__ dt3)
{
    int rid = blockIdx.x * 256 + threadIdx.x;
    if (rid >= 4 * 16 * 24) return;
    int b = rid / 384, rr = rid % 384, ry = rr / 24, rx = rr % 24;
    const int H = 128, W = 192;
    float w0 = dw[0];
    size_t base0 = ((size_t)b * H + ry * 8) * W + rx * 8;

    float q1[4][4], q2[4][4];
    #pragma unroll
    for (int yy = 0; yy < 4; ++yy) {
        float4 a0 = *reinterpret_cast<const float4*>(d1 + base0 + (2 * yy) * W);
        float4 a1 = *reinterpret_cast<const float4*>(d1 + base0 + (2 * yy) * W + 4);
        float4 a2 = *reinterpret_cast<const float4*>(d1 + base0 + (2 * yy + 1) * W);
        float4 a3 = *reinterpret_cast<const float4*>(d1 + base0 + (2 * yy + 1) * W + 4);
        float4 b0 = *reinterpret_cast<const float4*>(d2 + base0 + (2 * yy) * W);
        float4 b1 = *reinterpret_cast<const float4*>(d2 + base0 + (2 * yy) * W + 4);
        float4 b2 = *reinterpret_cast<const float4*>(d2 + base0 + (2 * yy + 1) * W);
        float4 b3 = *reinterpret_cast<const float4*>(d2 + base0 + (2 * yy + 1) * W + 4);
        float ra[2][8] = {{a0.x,a0.y,a0.z,a0.w,a1.x,a1.y,a1.z,a1.w},
                          {a2.x,a2.y,a2.z,a2.w,a3.x,a3.y,a3.z,a3.w}};
        float rb[2][8] = {{b0.x,b0.y,b0.z,b0.w,b1.x,b1.y,b1.z,b1.w},
                          {b2.x,b2.y,b2.z,b2.w,b3.x,b3.y,b3.z,b3.w}};
        #pragma unroll
        for (int e = 0; e < 2; ++e) {
            float o[8];
            #pragma unroll
            for (int xx = 0; xx < 8; ++xx) o[xx] = w0 * expf(-fabsf(ra[e][xx] - rb[e][xx]));
            *reinterpret_cast<float4*>(dt0 + base0 + (2 * yy + e) * W)     = make_float4(o[0], o[1], o[2], o[3]);
            *reinterpret_cast<float4*>(dt0 + base0 + (2 * yy + e) * W + 4) = make_float4(o[4], o[5], o[6], o[7]);
        }
        #pragma unroll
        for (int xx = 0; xx < 4; ++xx) {
            q1[yy][xx] = 0.25f * (ra[0][2 * xx] + ra[0][2 * xx + 1] + ra[1][2 * xx] + ra[1][2 * xx + 1]);
            q2[yy][xx] = 0.25f * (rb[0][2 * xx] + rb[0][2 * xx + 1] + rb[1][2 * xx] + rb[1][2 * xx + 1]);
        }
    }
    #pragma unroll
    for (int yy = 0; yy < 4; ++yy)
        #pragma unroll
        for (int xx = 0; xx < 4; ++xx)
            dt1[((size_t)b * 64 + ry * 4 + yy) * 96 + rx * 4 + xx] = w0 * expf(-fabsf(q1[yy][xx] - q2[yy][xx]));

    float r1[2][2], r2m[2][2];
    #pragma unroll
    for (int y = 0; y < 2; ++y)
        #pragma unroll
        for (int x = 0; x < 2; ++x) {
            r1[y][x]  = 0.25f * (q1[2 * y][2 * x] + q1[2 * y][2 * x + 1] + q1[2 * y + 1][2 * x] + q1[2 * y + 1][2 * x + 1]);
            r2m[y][x] = 0.25f * (q2[2 * y][2 * x] + q2[2 * y][2 * x + 1] + q2[2 * y + 1][2 * x] + q2[2 * y + 1][2 * x + 1]);
            dt2[((size_t)b * 32 + ry * 2 + y) * 48 + rx * 2 + x] = w0 * expf(-fabsf(r1[y][x] - r2m[y][x]));
        }
    float s1 = 0.25f * (r1[0][0] + r1[0][1] + r1[1][0] + r1[1][1]);
    float s2 = 0.25f * (r2m[0][0] + r2m[0][1] + r2m[1][0] + r2m[1][1]);
    dt3[((size_t)b * 16 + ry) * 24 + rx] = w0 * expf(-fabsf(s1 - s2));
}

// =====================================================================
extern "C" void kernel_launch(void* const* d_in, const int* in_sizes, int n_in,
                              void* d_out, int out_size, void* d_ws, size_t ws_size,
                              hipStream_t stream) {
    const float* f1 = (const float*)d_in[0];
    const float* f2 = (const float*)d_in[1];
    const float* d1 = (const float*)d_in[2];
    const float* d2 = (const float*)d_in[3];
    const float* dw = (const float*)d_in[4];
    float* out = (float*)d_out;
    float* ws  = (float*)d_ws;

    // ---------------- float workspace carve ----------------
    size_t o = 0;
    float* p1f1 = ws + o; o += (size_t)4 * 256 * 64 * 96;
    float* p2f1 = ws + o; o += (size_t)4 * 256 * 32 * 48;
    float* p3f1 = ws + o; o += (size_t)4 * 256 * 16 * 24;
    float* p1f2 = ws + o; o += (size_t)4 * 256 * 64 * 96;
    float* p2f2 = ws + o; o += (size_t)4 * 256 * 32 * 48;
    float* p3f2 = ws + o; o += (size_t)4 * 256 * 16 * 24;
    float* in1_0 = ws + o; o += (size_t)4 * 128 * 192;
    float* in1_1 = ws + o; o += (size_t)4 * 64 * 96;
    float* in1_2 = ws + o; o += (size_t)4 * 32 * 48;
    float* in1_3 = ws + o; o += (size_t)4 * 16 * 24;
    float* in2_0 = ws + o; o += (size_t)4 * 128 * 192;
    float* in2_1 = ws + o; o += (size_t)4 * 64 * 96;
    float* in2_2 = ws + o; o += (size_t)4 * 32 * 48;
    float* in2_3 = ws + o; o += (size_t)4 * 16 * 24;
    float* dt_0 = ws + o; o += (size_t)4 * 128 * 192;
    float* dt_1 = ws + o; o += (size_t)4 * 64 * 96;
    float* dt_2 = ws + o; o += (size_t)4 * 32 * 48;
    float* dt_3 = ws + o; o += (size_t)4 * 16 * 24;
    o = (o + 7) & ~(size_t)7;

    // ---------------- bf16 (ushort) workspace carve ----------------
    ushort_t* sws = (ushort_t*)(ws + o);
    const size_t L0 = (size_t)4 * 128 * 192 * 256;
    const size_t L1 = (size_t)4 * 64 * 96 * 256;
    const size_t L2 = (size_t)4 * 32 * 48 * 256;
    const size_t L3 = (size_t)4 * 16 * 24 * 256;
    const size_t FT = L0 + L1 + L2 + L3;
    ushort_t* f1n0 = sws;
    ushort_t* f1n1 = f1n0 + L0;
    ushort_t* f1n2 = f1n1 + L1;
    ushort_t* f1n3 = f1n2 + L2;
    ushort_t* f2n0 = sws + FT;
    ushort_t* f2n1 = f2n0 + L0;
    ushort_t* f2n2 = f2n1 + L1;
    ushort_t* f2n3 = f2n2 + L2;
    ushort_t* zblk = sws + 2 * FT;
    size_t need = o * 4 + (2 * FT + 256) * 2;
    if (ws_size < need) return;   // proven sufficient in rounds 1-2

    hipMemsetAsync(zblk, 0, 512, stream);

    // depth terms, all levels, one launch
    depth_kernel<<<dim3(6), 256, 0, stream>>>(d1, d2, dw, dt_0, dt_1, dt_2, dt_3);

    // prep chain, f1+f2 merged via blockIdx.y
    prep2_kernel<48, true ><<<dim3(4 * 64 * 4, 2), 256, 0, stream>>>(f1,   f2,   f1n0, f2n0, in1_0, in2_0, p1f1, p1f2, 128, 192);
    prep2_kernel<48, true ><<<dim3(4 * 32 * 2, 2), 256, 0, stream>>>(p1f1, p1f2, f1n1, f2n1, in1_1, in2_1, p2f1, p2f2, 64, 96);
    prep2_kernel<48, true ><<<dim3(4 * 16 * 1, 2), 256, 0, stream>>>(p2f1, p2f2, f1n2, f2n2, in1_2, in2_2, p3f1, p3f2, 32, 48);
    prep2_kernel<24, false><<<dim3(4 *  8 * 1, 2), 256, 0, stream>>>(p3f1, p3f2, f1n3, f2n3, in1_3, in2_3, nullptr, nullptr, 16, 24);

    // correlation: new LDS-staged kernel for L0-L2 (grids: 768/192/48, all %8==0)
    corr_mfma2_kernel<<<dim3(16 * 12 * 4), 256, 0, stream>>>(f1n0, f2n0, in1_0, in2_0, dt_0, out,           zblk, 128, 192, 12, 16);
    corr_mfma2_kernel<<<dim3( 8 *  6 * 4), 256, 0, stream>>>(f1n1, f2n1, in1_1, in2_1, dt_1, out + 7962624, zblk,  64,  96,  6,  8);
    corr_mfma2_kernel<<<dim3( 4 *  3 * 4), 256, 0, stream>>>(f1n2, f2n2, in1_2, in2_2, dt_2, out + 9953280, zblk,  32,  48,  3,  4);

    // L3 via round-2 kernel (24 blocks)
    corr_mfma_kernel<<<dim3(96 / 4), 256, 0, stream>>>(f1n3, f2n3, in1_3, in2_3, dt_3, out + 10450944, 16, 24, 6, 4,
                                                       (int)(2 * FT - (size_t)(f2n3 - sws)));
}

// Round 4
// 243.796 us; speedup vs baseline: 26.6672x; 1.2346x over previous
//
#include <hip/hip_runtime.h>
#include <hip/hip_bf16.h>

typedef __attribute__((ext_vector_type(8))) __bf16 bf16x8;
typedef __attribute__((ext_vector_type(4))) float f32x4;
typedef unsigned short ushort_t;
typedef unsigned int uint_t;

#define CCH 256
#define BB 4

__device__ __forceinline__ ushort_t f2b(float v) {
    __hip_bfloat16 h = __float2bfloat16(v);
    return *reinterpret_cast<ushort_t*>(&h);
}

__device__ __forceinline__ void gload16(const void* g, void* l) {
    __builtin_amdgcn_global_load_lds(
        (const __attribute__((address_space(1))) void*)g,
        (__attribute__((address_space(3))) void*)l, 16, 0, 0);
}

struct PrepPtrs {
    ushort_t* o0; ushort_t* o1; ushort_t* o2; ushort_t* o3;
    float* n0; float* n1; float* n2; float* n3;
};

// =====================================================================
// pyr_prep: ONE pass. Block = (b, 8-row stripe, 32-col chunk) of L0.
// Reads fp32 NCHW once (reg-prefetched), produces bf16 NHWC for ALL 4
// levels + all 4 invnorms. fp32 pooling chained through LDS (exact).
// LDS layout [pixel][channel] with XOR swizzle (cb ^= s(p)) so the
// channel-transpose read is b128 at structural-minimum banking.
// =====================================================================
__global__ __launch_bounds__(256, 3) void pyr_prep_kernel(
    const float* __restrict__ fa, const float* __restrict__ fb,
    PrepPtrs Pa, PrepPtrs Pb)
{
    const int H = 128, W = 192;
    const float* fin = blockIdx.y ? fb : fa;
    PrepPtrs P = blockIdx.y ? Pb : Pa;

    __shared__ float lds0[256 * 36];   // [p:256][c:32], stride 36, cb ^ s(p)
    __shared__ float lds1[64 * 36];    // [q:64][c:32]
    __shared__ float lds2[16 * 36];    // [s:16][c:32]
    __shared__ float red[256];

    int xc = blockIdx.x % 6;
    int ys = (blockIdx.x / 6) % 16;
    int b  = blockIdx.x / 96;
    int gx0 = xc * 32, gy0 = ys * 8;
    int t = threadIdx.x;

    float4 stg[8];
    auto issue = [&](int kc) {
        #pragma unroll
        for (int j = 0; j < 8; ++j) {
            int e = t + 256 * j;
            int c = e >> 6, r = (e >> 3) & 7, x4 = e & 7;
            stg[j] = *reinterpret_cast<const float4*>(
                fin + ((size_t)(b * 256 + kc * 32 + c) * H + gy0 + r) * W + gx0 + 4 * x4);
        }
    };

    float ssq0 = 0.f, ssq1 = 0.f, ssq2 = 0.f, ssq3 = 0.f;

    // persistent per-thread decode
    int r0 = t >> 5, x0v = t & 31;                 // L0 pixel owner
    size_t p0g = ((size_t)(b * H + gy0 + r0) * W + gx0 + x0v);
    int wv = t >> 6, q = t & 63, qy = q >> 4, qx = q & 15;   // L1 owner
    size_t l1g = ((size_t)(b * 64 + ys * 4 + qy) * 96 + xc * 16 + qx);
    int sI = t & 15, cb2 = t >> 4;                 // L2 owner (t<128)
    int sy2 = sI >> 3, sx2 = sI & 7;
    size_t l2g = ((size_t)(b * 32 + ys * 2 + sy2) * 48 + xc * 8 + sx2);
    int u3 = t & 3, cb3 = t >> 2;                  // L3 owner (t<32)
    size_t l3g = ((size_t)(b * 16 + ys) * 24 + xc * 4 + u3);

    int sp0 = ((t >> 2) + (t >> 5)) & 7;           // s(p) for p = t

    issue(0);
    #pragma unroll 1
    for (int kc = 0; kc < 8; ++kc) {
        // ---- A: regs -> lds0 (swizzled scatter) ----
        #pragma unroll
        for (int j = 0; j < 8; ++j) {
            int e = t + 256 * j;
            int c = e >> 6, r = (e >> 3) & 7, x4 = e & 7;
            int cb = c >> 2, c3 = c & 3;
            const float* sv = reinterpret_cast<const float*>(&stg[j]);
            #pragma unroll
            for (int i = 0; i < 4; ++i) {
                int p = r * 32 + 4 * x4 + i;
                int s = ((p >> 2) + (p >> 5)) & 7;
                lds0[36 * p + 4 * (cb ^ s) + c3] = sv[i];
            }
        }
        __syncthreads();
        if (kc < 7) issue(kc + 1);   // prefetch overlaps phases below

        // ---- B: L0 bf16 NHWC + ssq0 (thread owns pixel t) ----
        {
            uint_t uu[16];
            #pragma unroll
            for (int cb = 0; cb < 8; ++cb) {
                float4 v = *reinterpret_cast<const float4*>(&lds0[36 * t + 4 * (cb ^ sp0)]);
                ssq0 = fmaf(v.x, v.x, ssq0); ssq0 = fmaf(v.y, v.y, ssq0);
                ssq0 = fmaf(v.z, v.z, ssq0); ssq0 = fmaf(v.w, v.w, ssq0);
                uu[2 * cb]     = (uint_t)f2b(v.x) | ((uint_t)f2b(v.y) << 16);
                uu[2 * cb + 1] = (uint_t)f2b(v.z) | ((uint_t)f2b(v.w) << 16);
            }
            ushort_t* dst = P.o0 + p0g * CCH + kc * 32;
            *reinterpret_cast<uint4*>(dst +  0) = make_uint4(uu[0],  uu[1],  uu[2],  uu[3]);
            *reinterpret_cast<uint4*>(dst +  8) = make_uint4(uu[4],  uu[5],  uu[6],  uu[7]);
            *reinterpret_cast<uint4*>(dst + 16) = make_uint4(uu[8],  uu[9],  uu[10], uu[11]);
            *reinterpret_cast<uint4*>(dst + 24) = make_uint4(uu[12], uu[13], uu[14], uu[15]);
        }

        // ---- L1: pool 2x2 (thread owns (wv: 8ch, q: one L1 px)) ----
        {
            float a8[8] = {0.f, 0.f, 0.f, 0.f, 0.f, 0.f, 0.f, 0.f};
            #pragma unroll
            for (int dy = 0; dy < 2; ++dy)
                #pragma unroll
                for (int dx = 0; dx < 2; ++dx) {
                    int p = (2 * qy + dy) * 32 + 2 * qx + dx;
                    int s = ((p >> 2) + (p >> 5)) & 7;
                    #pragma unroll
                    for (int h = 0; h < 2; ++h) {
                        int cb = 2 * wv + h;
                        float4 v = *reinterpret_cast<const float4*>(&lds0[36 * p + 4 * (cb ^ s)]);
                        a8[4 * h + 0] += v.x; a8[4 * h + 1] += v.y;
                        a8[4 * h + 2] += v.z; a8[4 * h + 3] += v.w;
                    }
                }
            uint_t vv[4];
            #pragma unroll
            for (int i = 0; i < 8; ++i) { a8[i] *= 0.25f; ssq1 = fmaf(a8[i], a8[i], ssq1); }
            #pragma unroll
            for (int i = 0; i < 4; ++i)
                vv[i] = (uint_t)f2b(a8[2 * i]) | ((uint_t)f2b(a8[2 * i + 1]) << 16);
            *reinterpret_cast<uint4*>(P.o1 + l1g * CCH + kc * 32 + wv * 8)
                = make_uint4(vv[0], vv[1], vv[2], vv[3]);
            int s1 = ((q >> 2) + (q >> 5)) & 7;
            *reinterpret_cast<float4*>(&lds1[36 * q + 4 * ((2 * wv) ^ s1)])
                = make_float4(a8[0], a8[1], a8[2], a8[3]);
            *reinterpret_cast<float4*>(&lds1[36 * q + 4 * ((2 * wv + 1) ^ s1)])
                = make_float4(a8[4], a8[5], a8[6], a8[7]);
        }
        __syncthreads();

        // ---- L2: pool (t<128: owns (L2 px sI, 4ch block cb2)) ----
        if (t < 128) {
            float ax = 0.f, ay = 0.f, az = 0.f, aw = 0.f;
            #pragma unroll
            for (int dy = 0; dy < 2; ++dy)
                #pragma unroll
                for (int dx = 0; dx < 2; ++dx) {
                    int qq = (2 * sy2 + dy) * 16 + 2 * sx2 + dx;
                    int s1 = ((qq >> 2) + (qq >> 5)) & 7;
                    float4 v = *reinterpret_cast<const float4*>(&lds1[36 * qq + 4 * (cb2 ^ s1)]);
                    ax += v.x; ay += v.y; az += v.z; aw += v.w;
                }
            ax *= 0.25f; ay *= 0.25f; az *= 0.25f; aw *= 0.25f;
            ssq2 = fmaf(ax, ax, ssq2); ssq2 = fmaf(ay, ay, ssq2);
            ssq2 = fmaf(az, az, ssq2); ssq2 = fmaf(aw, aw, ssq2);
            uint_t w0 = (uint_t)f2b(ax) | ((uint_t)f2b(ay) << 16);
            uint_t w1 = (uint_t)f2b(az) | ((uint_t)f2b(aw) << 16);
            *reinterpret_cast<uint2*>(P.o2 + l2g * CCH + kc * 32 + cb2 * 4) = make_uint2(w0, w1);
            int s2 = ((sI >> 2) + (sI >> 5)) & 7;
            *reinterpret_cast<float4*>(&lds2[36 * sI + 4 * (cb2 ^ s2)])
                = make_float4(ax, ay, az, aw);
        }
        __syncthreads();

        // ---- L3: pool (t<32: owns (L3 px u3, 4ch block cb3)) ----
        if (t < 32) {
            float ax = 0.f, ay = 0.f, az = 0.f, aw = 0.f;
            #pragma unroll
            for (int dy = 0; dy < 2; ++dy)
                #pragma unroll
                for (int dx = 0; dx < 2; ++dx) {
                    int ss = dy * 8 + 2 * u3 + dx;
                    int s2 = ((ss >> 2) + (ss >> 5)) & 7;
                    float4 v = *reinterpret_cast<const float4*>(&lds2[36 * ss + 4 * (cb3 ^ s2)]);
                    ax += v.x; ay += v.y; az += v.z; aw += v.w;
                }
            ax *= 0.25f; ay *= 0.25f; az *= 0.25f; aw *= 0.25f;
            ssq3 = fmaf(ax, ax, ssq3); ssq3 = fmaf(ay, ay, ssq3);
            ssq3 = fmaf(az, az, ssq3); ssq3 = fmaf(aw, aw, ssq3);
            uint_t w0 = (uint_t)f2b(ax) | ((uint_t)f2b(ay) << 16);
            uint_t w1 = (uint_t)f2b(az) | ((uint_t)f2b(aw) << 16);
            *reinterpret_cast<uint2*>(P.o3 + l3g * CCH + kc * 32 + cb3 * 4) = make_uint2(w0, w1);
        }
    }

    // ---- invnorm reductions ----
    P.n0[p0g] = 1.f / fmaxf(sqrtf(ssq0), 1e-12f);
    red[t] = ssq1;
    __syncthreads();
    if (t < 64) {
        float sm = red[t] + red[t + 64] + red[t + 128] + red[t + 192];
        P.n1[((size_t)(b * 64 + ys * 4 + (t >> 4)) * 96 + xc * 16 + (t & 15))]
            = 1.f / fmaxf(sqrtf(sm), 1e-12f);
    }
    __syncthreads();
    if (t < 128) red[t] = ssq2;
    __syncthreads();
    if (t < 16) {
        float sm = 0.f;
        #pragma unroll
        for (int c = 0; c < 8; ++c) sm += red[t + 16 * c];
        P.n2[((size_t)(b * 32 + ys * 2 + (t >> 3)) * 48 + xc * 8 + (t & 7))]
            = 1.f / fmaxf(sqrtf(sm), 1e-12f);
    }
    __syncthreads();
    if (t < 32) red[t] = ssq3;
    __syncthreads();
    if (t < 4) {
        float sm = 0.f;
        #pragma unroll
        for (int c = 0; c < 8; ++c) sm += red[t + 4 * c];
        P.n3[((size_t)(b * 16 + ys) * 24 + xc * 4 + t)]
            = 1.f / fmaxf(sqrtf(sm), 1e-12f);
    }
}

// =====================================================================
// corr_mfma2: LDS-staged, double-buffered (unchanged from round 3)
// =====================================================================
__global__ __launch_bounds__(256, 2) void corr_mfma2_kernel(
    const ushort_t* __restrict__ f1n, const ushort_t* __restrict__ f2n,
    const float* __restrict__ invn1, const float* __restrict__ invn2,
    const float* __restrict__ dt, float* __restrict__ out,
    const ushort_t* __restrict__ zblk, int H, int W, int TX, int TY)
{
    __shared__ char smem[65536];
    char* As = smem;
    char* Bs = smem + 16384;

    int bid = blockIdx.x;
    int cpx = gridDim.x >> 3;
    int swz = (bid & 7) * cpx + (bid >> 3);
    int tx = swz % TX;
    int ty = (swz / TX) % TY;
    int b  = swz / (TX * TY);
    int x0 = tx * 16, y0 = ty * 8;

    int tid = threadIdx.x;
    int w = tid >> 6, lane = tid & 63;
    int kg = lane >> 4, col = lane & 15;
    int r2 = col >> 2, c2 = col & 3;
    int sy = w >> 1, p = w & 1;

    const ushort_t* srcA[2]; char* ldsA[2];
    #pragma unroll
    for (int q = 0; q < 2; ++q) {
        int qq = w * 2 + q;
        int kgs = qq >> 1, reg = qq & 1;
        int slot = reg * 64 + lane;
        int ly = slot >> 4, lxp = slot & 15;
        int lx = lxp ^ (4 * (ly & 1));
        srcA[q] = f1n + ((size_t)((b * H + y0 + ly) * W) + x0 + lx) * CCH + kgs * 8;
        ldsA[q] = As + qq * 1024;
    }
    const ushort_t* srcB[6]; int advB[6]; char* ldsB[6];
    #pragma unroll
    for (int q = 0; q < 6; ++q) {
        int qq = w * 6 + q;
        int kgs = qq / 6, reg = qq % 6;
        int slot = reg * 64 + lane;
        int wy = slot / 24, wxp = slot % 24;
        int wx = wxp ^ (4 * (wy & 1));
        int py = y0 - 4 + wy, px = x0 - 4 + wx;
        bool v = (py >= 0) && (py < H) && (px >= 0) && (px < W);
        srcB[q] = v ? (f2n + ((size_t)((b * H + py) * W) + px) * CCH + kgs * 8) : zblk;
        advB[q] = v ? 32 : 0;
        ldsB[q] = Bs + qq * 1024;
    }

    int aoff[2], boff[3][4];
    #pragma unroll
    for (int s = 0; s < 2; ++s) {
        int sxs = 2 * p + s;
        int ly = 4 * sy + r2;
        int lx = (4 * sxs + c2) ^ (4 * (ly & 1));
        aoff[s] = kg * 2048 + (ly * 16 + lx) * 16;
    }
    #pragma unroll
    for (int i = 0; i < 3; ++i)
        #pragma unroll
        for (int j = 0; j < 4; ++j) {
            int wy = 4 * (sy + i) + r2;
            int wx = (4 * (2 * p + j) + c2) ^ (4 * (wy & 1));
            boff[i][j] = kg * 6144 + (wy * 24 + wx) * 16;
        }

    f32x4 acc0[3][3] = {};
    f32x4 acc1[3][3] = {};

    #pragma unroll
    for (int q = 0; q < 2; ++q) { gload16(srcA[q], ldsA[q]); srcA[q] += 32; }
    #pragma unroll
    for (int q = 0; q < 6; ++q) { gload16(srcB[q], ldsB[q]); srcB[q] += advB[q]; }
    asm volatile("s_waitcnt vmcnt(0)" ::: "memory");
    __builtin_amdgcn_s_barrier();
    __builtin_amdgcn_sched_barrier(0);

    int buf = 0;
    #pragma unroll 1
    for (int kc = 0; kc < 8; ++kc) {
        if (kc < 7) {
            int boA = (buf ^ 1) * 8192;
            int boB = (buf ^ 1) * 24576;
            #pragma unroll
            for (int q = 0; q < 2; ++q) { gload16(srcA[q], ldsA[q] + boA); srcA[q] += 32; }
            #pragma unroll
            for (int q = 0; q < 6; ++q) { gload16(srcB[q], ldsB[q] + boB); srcB[q] += advB[q]; }
        }
        const char* Ab = As + buf * 8192;
        const char* Bb = Bs + buf * 24576;
        bf16x8 av0 = *(const bf16x8*)(Ab + aoff[0]);
        bf16x8 av1 = *(const bf16x8*)(Ab + aoff[1]);
        #pragma unroll
        for (int i = 0; i < 3; ++i) {
            #pragma unroll
            for (int j = 0; j < 4; ++j) {
                bf16x8 bv = *(const bf16x8*)(Bb + boff[i][j]);
                if (j < 3) acc0[i][j]     = __builtin_amdgcn_mfma_f32_16x16x32_bf16(av0, bv, acc0[i][j], 0, 0, 0);
                if (j > 0) acc1[i][j - 1] = __builtin_amdgcn_mfma_f32_16x16x32_bf16(av1, bv, acc1[i][j - 1], 0, 0, 0);
            }
        }
        if (kc < 7) {
            __builtin_amdgcn_sched_barrier(0);
            asm volatile("s_waitcnt vmcnt(0)" ::: "memory");
            __builtin_amdgcn_s_barrier();
            __builtin_amdgcn_sched_barrier(0);
        }
        buf ^= 1;
    }

    float inv1v[2][4], dtv[2][4];
    #pragma unroll
    for (int s = 0; s < 2; ++s) {
        int sxs = 2 * p + s;
        #pragma unroll
        for (int rr = 0; rr < 4; ++rr) {
            int m = kg * 4 + rr;
            int iy = m >> 2, ix = m & 3;
            int pix = (b * H + y0 + 4 * sy + iy) * W + x0 + 4 * sxs + ix;
            inv1v[s][rr] = invn1[pix];
            dtv[s][rr]   = dt[pix];
        }
    }
    #pragma unroll
    for (int s = 0; s < 2; ++s) {
        int sxs = 2 * p + s;
        #pragma unroll
        for (int i = 0; i < 3; ++i) {
            #pragma unroll
            for (int jj = 0; jj < 3; ++jj) {
                int wy = 4 * (sy + i) + r2;
                int wxr = 4 * (sxs + jj) + c2;
                int py = y0 - 4 + wy, px = x0 - 4 + wxr;
                bool v = (py >= 0) && (py < H) && (px >= 0) && (px < W);
                float i2 = v ? invn2[(b * H + py) * W + px] : 0.f;
                f32x4 a = (s == 0) ? acc0[i][jj] : acc1[i][jj];
                #pragma unroll
                for (int rr = 0; rr < 4; ++rr) {
                    int m = kg * 4 + rr;
                    int iy = m >> 2, ix = m & 3;
                    int oy = iy + 8 - (4 * i + r2);
                    int ox = ix + 8 - (4 * jj + c2);
                    if (oy >= 0 && oy < 9 && ox >= 0 && ox < 9) {
                        int gy = y0 + 4 * sy + iy, gx = x0 + 4 * sxs + ix;
                        out[((size_t)(b * 81 + oy * 9 + ox) * H + gy) * W + gx]
                            = a[rr] * inv1v[s][rr] * i2 + dtv[s][rr];
                    }
                }
            }
        }
    }
}

// =====================================================================
// corr_mfma (round-2, known good) — L3 only
// =====================================================================
__global__ __launch_bounds__(256) void corr_mfma_kernel(
    const ushort_t* __restrict__ f1n, const ushort_t* __restrict__ f2n,
    const float* __restrict__ invn1, const float* __restrict__ invn2,
    const float* __restrict__ dt, float* __restrict__ out,
    int H, int W, int TX, int TY, int zoff)
{
    int wid  = threadIdx.x >> 6;
    int lane = threadIdx.x & 63;
    int tile = blockIdx.x * 4 + wid;
    int ntiles = BB * TY * TX;
    if (tile >= ntiles) return;
    int tx = tile % TX;
    int ty = (tile / TX) % TY;
    int b  = tile / (TX * TY);
    int x0 = tx * 4, y0 = ty * 4;

    int col = lane & 15;
    int kg  = lane >> 4;

    int iyA = col >> 2, ixA = col & 3;
    int a_off = (((b * H + y0 + iyA) * W) + x0 + ixA) * CCH + kg * 8;

    int b_off[9];
    uint_t vmask = 0;
    #pragma unroll
    for (int tt = 0; tt < 9; ++tt) {
        int w = tt * 16 + col;
        int wy = w / 12, wx = w % 12;
        int py = y0 + wy - 4, px = x0 + wx - 4;
        bool v = (py >= 0) && (py < H) && (px >= 0) && (px < W);
        b_off[tt] = v ? (((b * H + py) * W + px) * CCH + kg * 8) : (zoff + kg * 8);
        if (v) vmask |= (1u << tt);
    }

    f32x4 acc[9] = {};
    #pragma unroll
    for (int kb = 0; kb < 8; ++kb) {
        bf16x8 av = *reinterpret_cast<const bf16x8*>(f1n + a_off + kb * 32);
        #pragma unroll
        for (int tt = 0; tt < 9; ++tt) {
            bf16x8 bv = *reinterpret_cast<const bf16x8*>(f2n + b_off[tt] + kb * 32);
            acc[tt] = __builtin_amdgcn_mfma_f32_16x16x32_bf16(av, bv, acc[tt], 0, 0, 0);
        }
    }

    float inv1[4], dts[4];
    #pragma unroll
    for (int r = 0; r < 4; ++r) {
        int m = kg * 4 + r;
        int iy = m >> 2, ix = m & 3;
        int pix = (b * H + y0 + iy) * W + x0 + ix;
        inv1[r] = invn1[pix];
        dts[r]  = dt[pix];
    }
    #pragma unroll
    for (int tt = 0; tt < 9; ++tt) {
        int w = tt * 16 + col;
        int wy = w / 12, wx = w % 12;
        int py = y0 + wy - 4, px = x0 + wx - 4;
        float i2 = ((vmask >> tt) & 1u) ? invn2[(b * H + py) * W + px] : 0.f;
        #pragma unroll
        for (int r = 0; r < 4; ++r) {
            int m = kg * 4 + r;
            int iy = m >> 2, ix = m & 3;
            int oy = iy + 8 - wy, ox = ix + 8 - wx;
            if (oy >= 0 && oy < 9 && ox >= 0 && ox < 9) {
                int o = oy * 9 + ox;
                out[((size_t)(b * 81 + o) * H + (y0 + iy)) * W + (x0 + ix)]
                    = acc[tt][r] * inv1[r] * i2 + dts[r];
            }
        }
    }
}

// =====================================================================
// depth: one thread owns an 8x8 L0 patch; dt for all 4 levels
// =====================================================================
__global__ __launch_bounds__(256) void depth_kernel(
    const float* __restrict__ d1, const float* __restrict__ d2,
    const float* __restrict__ dw,
    float* __restrict__ dt0, float* __restrict__ dt1,
    float* __restrict__ dt2, float* __restrict__ dt3)
{
    int rid = blockIdx.x * 256 + threadIdx.x;
    if (rid >= 4 * 16 * 24) return;
    int b = rid / 384, rr = rid % 384, ry = rr / 24, rx = rr % 24;
    const int H = 128, W = 192;
    float w0 = dw[0];
    size_t base0 = ((size_t)b * H + ry * 8) * W + rx * 8;

    float q1[4][4], q2[4][4];
    #pragma unroll
    for (int yy = 0; yy < 4; ++yy) {
        float4 a0 = *reinterpret_cast<const float4*>(d1 + base0 + (2 * yy) * W);
        float4 a1 = *reinterpret_cast<const float4*>(d1 + base0 + (2 * yy) * W + 4);
        float4 a2 = *reinterpret_cast<const float4*>(d1 + base0 + (2 * yy + 1) * W);
        float4 a3 = *reinterpret_cast<const float4*>(d1 + base0 + (2 * yy + 1) * W + 4);
        float4 b0 = *reinterpret_cast<const float4*>(d2 + base0 + (2 * yy) * W);
        float4 b1 = *reinterpret_cast<const float4*>(d2 + base0 + (2 * yy) * W + 4);
        float4 b2 = *reinterpret_cast<const float4*>(d2 + base0 + (2 * yy + 1) * W);
        float4 b3 = *reinterpret_cast<const float4*>(d2 + base0 + (2 * yy + 1) * W + 4);
        float ra[2][8] = {{a0.x,a0.y,a0.z,a0.w,a1.x,a1.y,a1.z,a1.w},
                          {a2.x,a2.y,a2.z,a2.w,a3.x,a3.y,a3.z,a3.w}};
        float rb[2][8] = {{b0.x,b0.y,b0.z,b0.w,b1.x,b1.y,b1.z,b1.w},
                          {b2.x,b2.y,b2.z,b2.w,b3.x,b3.y,b3.z,b3.w}};
        #pragma unroll
        for (int e = 0; e < 2; ++e) {
            float o[8];
            #pragma unroll
            for (int xx = 0; xx < 8; ++xx) o[xx] = w0 * expf(-fabsf(ra[e][xx] - rb[e][xx]));
            *reinterpret_cast<float4*>(dt0 + base0 + (2 * yy + e) * W)     = make_float4(o[0], o[1], o[2], o[3]);
            *reinterpret_cast<float4*>(dt0 + base0 + (2 * yy + e) * W + 4) = make_float4(o[4], o[5], o[6], o[7]);
        }
        #pragma unroll
        for (int xx = 0; xx < 4; ++xx) {
            q1[yy][xx] = 0.25f * (ra[0][2 * xx] + ra[0][2 * xx + 1] + ra[1][2 * xx] + ra[1][2 * xx + 1]);
            q2[yy][xx] = 0.25f * (rb[0][2 * xx] + rb[0][2 * xx + 1] + rb[1][2 * xx] + rb[1][2 * xx + 1]);
        }
    }
    #pragma unroll
    for (int yy = 0; yy < 4; ++yy)
        #pragma unroll
        for (int xx = 0; xx < 4; ++xx)
            dt1[((size_t)b * 64 + ry * 4 + yy) * 96 + rx * 4 + xx] = w0 * expf(-fabsf(q1[yy][xx] - q2[yy][xx]));

    float r1[2][2], r2m[2][2];
    #pragma unroll
    for (int y = 0; y < 2; ++y)
        #pragma unroll
        for (int x = 0; x < 2; ++x) {
            r1[y][x]  = 0.25f * (q1[2 * y][2 * x] + q1[2 * y][2 * x + 1] + q1[2 * y + 1][2 * x] + q1[2 * y + 1][2 * x + 1]);
            r2m[y][x] = 0.25f * (q2[2 * y][2 * x] + q2[2 * y][2 * x + 1] + q2[2 * y + 1][2 * x] + q2[2 * y + 1][2 * x + 1]);
            dt2[((size_t)b * 32 + ry * 2 + y) * 48 + rx * 2 + x] = w0 * expf(-fabsf(r1[y][x] - r2m[y][x]));
        }
    float s1 = 0.25f * (r1[0][0] + r1[0][1] + r1[1][0] + r1[1][1]);
    float s2 = 0.25f * (r2m[0][0] + r2m[0][1] + r2m[1][0] + r2m[1][1]);
    dt3[((size_t)b * 16 + ry) * 24 + rx] = w0 * expf(-fabsf(s1 - s2));
}

// =====================================================================
extern "C" void kernel_launch(void* const* d_in, const int* in_sizes, int n_in,
                              void* d_out, int out_size, void* d_ws, size_t ws_size,
                              hipStream_t stream) {
    const float* f1 = (const float*)d_in[0];
    const float* f2 = (const float*)d_in[1];
    const float* d1 = (const float*)d_in[2];
    const float* d2 = (const float*)d_in[3];
    const float* dw = (const float*)d_in[4];
    float* out = (float*)d_out;
    float* ws  = (float*)d_ws;

    // ---------------- float workspace carve ----------------
    size_t o = 0;
    float* in1_0 = ws + o; o += (size_t)4 * 128 * 192;
    float* in1_1 = ws + o; o += (size_t)4 * 64 * 96;
    float* in1_2 = ws + o; o += (size_t)4 * 32 * 48;
    float* in1_3 = ws + o; o += (size_t)4 * 16 * 24;
    float* in2_0 = ws + o; o += (size_t)4 * 128 * 192;
    float* in2_1 = ws + o; o += (size_t)4 * 64 * 96;
    float* in2_2 = ws + o; o += (size_t)4 * 32 * 48;
    float* in2_3 = ws + o; o += (size_t)4 * 16 * 24;
    float* dt_0 = ws + o; o += (size_t)4 * 128 * 192;
    float* dt_1 = ws + o; o += (size_t)4 * 64 * 96;
    float* dt_2 = ws + o; o += (size_t)4 * 32 * 48;
    float* dt_3 = ws + o; o += (size_t)4 * 16 * 24;
    o = (o + 7) & ~(size_t)7;

    // ---------------- bf16 (ushort) workspace carve ----------------
    ushort_t* sws = (ushort_t*)(ws + o);
    const size_t L0 = (size_t)4 * 128 * 192 * 256;
    const size_t L1 = (size_t)4 * 64 * 96 * 256;
    const size_t L2 = (size_t)4 * 32 * 48 * 256;
    const size_t L3 = (size_t)4 * 16 * 24 * 256;
    const size_t FT = L0 + L1 + L2 + L3;
    ushort_t* f1n0 = sws;
    ushort_t* f1n1 = f1n0 + L0;
    ushort_t* f1n2 = f1n1 + L1;
    ushort_t* f1n3 = f1n2 + L2;
    ushort_t* f2n0 = sws + FT;
    ushort_t* f2n1 = f2n0 + L0;
    ushort_t* f2n2 = f2n1 + L1;
    ushort_t* f2n3 = f2n2 + L2;
    ushort_t* zblk = sws + 2 * FT;
    size_t need = o * 4 + (2 * FT + 256) * 2;
    if (ws_size < need) return;   // proven sufficient in prior rounds

    hipMemsetAsync(zblk, 0, 512, stream);

    depth_kernel<<<dim3(6), 256, 0, stream>>>(d1, d2, dw, dt_0, dt_1, dt_2, dt_3);

    // fused pyramid prep: ONE kernel, both tensors, all 4 levels
    PrepPtrs Pa = { f1n0, f1n1, f1n2, f1n3, in1_0, in1_1, in1_2, in1_3 };
    PrepPtrs Pb = { f2n0, f2n1, f2n2, f2n3, in2_0, in2_1, in2_2, in2_3 };
    pyr_prep_kernel<<<dim3(384, 2), 256, 0, stream>>>(f1, f2, Pa, Pb);

    // correlation
    corr_mfma2_kernel<<<dim3(16 * 12 * 4), 256, 0, stream>>>(f1n0, f2n0, in1_0, in2_0, dt_0, out,           zblk, 128, 192, 12, 16);
    corr_mfma2_kernel<<<dim3( 8 *  6 * 4), 256, 0, stream>>>(f1n1, f2n1, in1_1, in2_1, dt_1, out + 7962624, zblk,  64,  96,  6,  8);
    corr_mfma2_kernel<<<dim3( 4 *  3 * 4), 256, 0, stream>>>(f1n2, f2n2, in1_2, in2_2, dt_2, out + 9953280, zblk,  32,  48,  3,  4);
    corr_mfma_kernel<<<dim3(96 / 4), 256, 0, stream>>>(f1n3, f2n3, in1_3, in2_3, dt_3, out + 10450944, 16, 24, 6, 4,
                                                       (int)(2 * FT - (size_t)(f2n3 - sws)));
}